// Round 1
// baseline (80.292 us; speedup 1.0000x reference)
//
#include <hip/hip_runtime.h>
#include <hip/hip_bf16.h>

// Factorized NaiveBias2d:
//   out[n, a*32+b, h, d] = sum_e bias[h,b,e]*Vc[n,e,h,d] + sum_c bias[h,a,c]*Ve[n,c,h,d]
//   bias[h,j,i] = w[h, (32 + j - i) % 63]
//   Vc[n,e,h,d] = sum_c v[n, c*32+e, h, d]   Ve[n,c,h,d] = sum_e v[n, c*32+e, h, d]
//
// Constants: BATCH=8, SEQ=1024 (32x32), HEADS=8, DIM=64 -> hd stride 512.

#define HD 512          // h*64+d contiguous extent
#define S  32           // grid side

// ---------------- Stage 1: reductions over c (Vc) and e (Ve) ----------------
// grid 512 blocks x 512 threads. Blocks 0..255: Vc (block=n*32+e).
// Blocks 256..511: Ve (block=n*32+c). Thread = hd position. Coalesced.
__global__ __launch_bounds__(512) void reduce_kernel(
    const float* __restrict__ v, float* __restrict__ Vc, float* __restrict__ Ve) {
  int block = blockIdx.x;
  int hd = threadIdx.x;                 // 0..511
  bool isVc = block < 256;
  int b2 = isVc ? block : block - 256;  // n*32 + x
  int n = b2 >> 5;
  int x = b2 & 31;                      // e for Vc, c for Ve
  const float* base = v + ((size_t)n * 1024) * HD + hd;
  float acc = 0.f;
  if (isVc) {
#pragma unroll
    for (int c = 0; c < 32; ++c) acc += base[(size_t)(c * S + x) * HD];
    Vc[(size_t)b2 * HD + hd] = acc;
  } else {
#pragma unroll
    for (int e = 0; e < 32; ++e) acc += base[(size_t)(x * S + e) * HD];
    Ve[(size_t)b2 * HD + hd] = acc;
  }
}

// ---------------- Stage 2: per-(n,h) small matmuls -> T1, T2 ----------------
// T1[n,b,h,d] = sum_e bias[h,b,e]*Vc[n,e,h,d]
// T2[n,a,h,d] = sum_c bias[h,a,c]*Ve[n,c,h,d]
// grid 64 blocks (n*8+h) x 256 threads. LDS: bias 4KB + Vc tile 8KB + Ve tile 8KB.
__global__ __launch_bounds__(256) void terms_kernel(
    const float* __restrict__ w,
    const float* __restrict__ Vc, const float* __restrict__ Ve,
    float* __restrict__ T1, float* __restrict__ T2) {
  __shared__ float bias_s[32][32];
  __shared__ float vc_s[32][64];
  __shared__ float ve_s[32][64];
  int nh = blockIdx.x;
  int n = nh >> 3, h = nh & 7;
  int t = threadIdx.x;

  // bias[b][e] = w[h, (32 + b - e) % 63]; (32+b-e) in [1,63], %63 -> [0,62]
  for (int idx = t; idx < 1024; idx += 256) {
    int b = idx >> 5, e = idx & 31;
    int k = (32 + b - e) % 63;
    bias_s[b][e] = w[h * 63 + k];
  }
  for (int idx = t; idx < 2048; idx += 256) {
    int e = idx >> 6, d = idx & 63;
    size_t g = (size_t)(n * S + e) * HD + h * 64 + d;
    vc_s[e][d] = Vc[g];
    ve_s[e][d] = Ve[g];
  }
  __syncthreads();

  int d = t & 63;       // lanes of a wave share bg -> bias_s reads broadcast
  int bg = t >> 6;      // 0..3
  for (int b = bg; b < 32; b += 4) {
    float a1 = 0.f, a2 = 0.f;
#pragma unroll
    for (int e = 0; e < 32; ++e) {
      a1 += bias_s[b][e] * vc_s[e][d];
      a2 += bias_s[b][e] * ve_s[e][d];
    }
    size_t g = (size_t)(n * S + b) * HD + h * 64 + d;
    T1[g] = a1;   // indexed [n][b][h][d]
    T2[g] = a2;   // indexed [n][a][h][d]
  }
}

// ---------------- Stage 3: broadcast add -> out ----------------
// out[((n*1024 + a*32 + b)*8 + h)*64 + d] = T1[n,b,h,d] + T2[n,a,h,d]
// One float4 per thread; T1/T2 (1 MB total) stay cache-resident.
__global__ __launch_bounds__(256) void out_kernel(
    const float4* __restrict__ T1, const float4* __restrict__ T2,
    float4* __restrict__ out) {
  int idx = blockIdx.x * 256 + threadIdx.x;   // 0 .. 1048575 (float4 units)
  int d4 = idx & 15;
  int h  = (idx >> 4) & 7;
  int j  = (idx >> 7) & 1023;
  int n  = idx >> 17;
  int b = j & 31, a = j >> 5;
  float4 x = T1[((n * S + b) * 8 + h) * 16 + d4];
  float4 y = T2[((n * S + a) * 8 + h) * 16 + d4];
  out[idx] = make_float4(x.x + y.x, x.y + y.y, x.z + y.z, x.w + y.w);
}

extern "C" void kernel_launch(void* const* d_in, const int* in_sizes, int n_in,
                              void* d_out, int out_size, void* d_ws, size_t ws_size,
                              hipStream_t stream) {
  const float* v = (const float*)d_in[0];   // (8,1024,8,64) fp32
  const float* w = (const float*)d_in[1];   // (1,8,63)      fp32
  float* out = (float*)d_out;               // (8,1024,8,64) fp32
  float* ws  = (float*)d_ws;

  float* Vc = ws;                 // 131072 floats
  float* Ve = ws + 131072;        // 131072
  float* T1 = ws + 262144;        // 131072
  float* T2 = ws + 393216;        // 131072  (2 MB total)

  reduce_kernel<<<512, 512, 0, stream>>>(v, Vc, Ve);
  terms_kernel<<<64, 256, 0, stream>>>(w, Vc, Ve, T1, T2);
  out_kernel<<<4096, 256, 0, stream>>>((const float4*)T1, (const float4*)T2,
                                       (float4*)out);
}

// Round 2
// 79.184 us; speedup vs baseline: 1.0140x; 1.0140x over previous
//
#include <hip/hip_runtime.h>
#include <hip/hip_bf16.h>

// Factorized NaiveBias2d:
//   out[n, a*32+b, h, d] = sum_e bias[h,b,e]*Vc[n,e,h,d] + sum_c bias[h,a,c]*Ve[n,c,h,d]
//   bias[h,j,i] = w[h, (32 + j - i) % 63]
//   Vc[n,e,h,d] = sum_c v[n, c*32+e, h, d]   Ve[n,c,h,d] = sum_e v[n, c*32+e, h, d]
//
// Constants: BATCH=8, SEQ=1024 (32x32), HEADS=8, DIM=64 -> hd stride 512 floats
// = 128 float4.

#define S 32
#define HD4 128   // hd extent in float4 units

// ---------------- Stage 1: reductions over c (Vc) and e (Ve) ----------------
// grid 512 blocks x 128 threads (float4 per thread over hd).
// Blocks 0..255: Vc (block=n*32+e). Blocks 256..511: Ve (block=n*32+c).
// Each wave-load is 64 lanes x 16 B = 1 KiB contiguous (coalescing sweet spot).
__global__ __launch_bounds__(128) void reduce_kernel(
    const float4* __restrict__ v, float4* __restrict__ Vc,
    float4* __restrict__ Ve) {
  int block = blockIdx.x;
  int t = threadIdx.x;                  // 0..127
  bool isVc = block < 256;
  int b2 = isVc ? block : block - 256;  // n*32 + x
  int n = b2 >> 5;
  int x = b2 & 31;                      // e for Vc, c for Ve
  const float4* base = v + (size_t)n * 1024 * HD4 + t;
  float4 acc = make_float4(0.f, 0.f, 0.f, 0.f);
  if (isVc) {
#pragma unroll
    for (int c = 0; c < 32; ++c) {
      float4 r = base[(size_t)(c * S + x) * HD4];
      acc.x += r.x; acc.y += r.y; acc.z += r.z; acc.w += r.w;
    }
    Vc[(size_t)b2 * HD4 + t] = acc;
  } else {
#pragma unroll
    for (int e = 0; e < 32; ++e) {
      float4 r = base[(size_t)(x * S + e) * HD4];
      acc.x += r.x; acc.y += r.y; acc.z += r.z; acc.w += r.w;
    }
    Ve[(size_t)b2 * HD4 + t] = acc;
  }
}

// ---------------- Stage 2: per-(n,h) small matmuls -> T1, T2 ----------------
// T1[n,b,h,d] = sum_e bias[h,b,e]*Vc[n,e,h,d]
// T2[n,a,h,d] = sum_c bias[h,a,c]*Ve[n,c,h,d]
// grid 64 blocks (n*8+h) x 256 threads. LDS: bias 4KB + Vc tile 8KB + Ve 8KB.
__global__ __launch_bounds__(256) void terms_kernel(
    const float* __restrict__ w,
    const float* __restrict__ Vc, const float* __restrict__ Ve,
    float* __restrict__ T1, float* __restrict__ T2) {
  __shared__ float bias_s[32][32];
  __shared__ float vc_s[32][64];
  __shared__ float ve_s[32][64];
  int nh = blockIdx.x;
  int n = nh >> 3, h = nh & 7;
  int t = threadIdx.x;

  // bias[b][e] = w[h, (32 + b - e) % 63]; (32+b-e) in [1,63], %63 -> [0,62]
  for (int idx = t; idx < 1024; idx += 256) {
    int b = idx >> 5, e = idx & 31;
    int k = (32 + b - e) % 63;
    bias_s[b][e] = w[h * 63 + k];
  }
  // Stage Vc/Ve tiles as float4: 32 rows x 16 float4 = 512 float4 each.
  for (int idx = t; idx < 512; idx += 256) {
    int e = idx >> 4, d4 = idx & 15;
    size_t g = ((size_t)(n * S + e) * 8 + h) * 16 + d4;  // float4 units of HD
    float4 a = ((const float4*)Vc)[g];
    float4 b = ((const float4*)Ve)[g];
    vc_s[e][d4 * 4 + 0] = a.x; vc_s[e][d4 * 4 + 1] = a.y;
    vc_s[e][d4 * 4 + 2] = a.z; vc_s[e][d4 * 4 + 3] = a.w;
    ve_s[e][d4 * 4 + 0] = b.x; ve_s[e][d4 * 4 + 1] = b.y;
    ve_s[e][d4 * 4 + 2] = b.z; ve_s[e][d4 * 4 + 3] = b.w;
  }
  __syncthreads();

  int d = t & 63;       // lanes of a wave share bg -> bias_s reads broadcast
  int bg = t >> 6;      // 0..3
  for (int b = bg; b < 32; b += 4) {
    float a1 = 0.f, a2 = 0.f;
#pragma unroll
    for (int e = 0; e < 32; ++e) {
      a1 += bias_s[b][e] * vc_s[e][d];
      a2 += bias_s[b][e] * ve_s[e][d];
    }
    size_t g = (size_t)(n * S + b) * 512 + h * 64 + d;
    T1[g] = a1;   // indexed [n][b][h][d]
    T2[g] = a2;   // indexed [n][a][h][d]
  }
}

// ---------------- Stage 3: broadcast add -> out ----------------
// out[((n*1024 + a*32 + b)*8 + h)*64 + d] = T1[n,b,h,d] + T2[n,a,h,d]
// One float4 per thread; T1/T2 (1 MB total) stay cache-resident.
__global__ __launch_bounds__(256) void out_kernel(
    const float4* __restrict__ T1, const float4* __restrict__ T2,
    float4* __restrict__ out) {
  int idx = blockIdx.x * 256 + threadIdx.x;   // 0 .. 1048575 (float4 units)
  int d4 = idx & 15;
  int h  = (idx >> 4) & 7;
  int j  = (idx >> 7) & 1023;
  int n  = idx >> 17;
  int b = j & 31, a = j >> 5;
  float4 x = T1[((n * S + b) * 8 + h) * 16 + d4];
  float4 y = T2[((n * S + a) * 8 + h) * 16 + d4];
  out[idx] = make_float4(x.x + y.x, x.y + y.y, x.z + y.z, x.w + y.w);
}

extern "C" void kernel_launch(void* const* d_in, const int* in_sizes, int n_in,
                              void* d_out, int out_size, void* d_ws, size_t ws_size,
                              hipStream_t stream) {
  const float* v = (const float*)d_in[0];   // (8,1024,8,64) fp32
  const float* w = (const float*)d_in[1];   // (1,8,63)      fp32
  float* out = (float*)d_out;               // (8,1024,8,64) fp32
  float* ws  = (float*)d_ws;

  float* Vc = ws;                 // 131072 floats
  float* Ve = ws + 131072;        // 131072
  float* T1 = ws + 262144;        // 131072
  float* T2 = ws + 393216;        // 131072  (2 MB total)

  reduce_kernel<<<512, 128, 0, stream>>>((const float4*)v, (float4*)Vc,
                                         (float4*)Ve);
  terms_kernel<<<64, 256, 0, stream>>>(w, Vc, Ve, T1, T2);
  out_kernel<<<4096, 256, 0, stream>>>((const float4*)T1, (const float4*)T2,
                                       (float4*)out);
}